// Round 2
// baseline (31.801 us; speedup 1.0000x reference)
//
#include <hip/hip_runtime.h>
#include <hip/hip_bf16.h>
#include <math.h>

// MultiVariateAttention: out[b,u] = exp(mvn_logpdf(x[b]; mu[u], diag(s[u])))
// B = U = 4096, D = 16, fp32 in/out.
//
// log2(out[b,u]) = sum_d x_d*(A1[u,d] + x_d*A2[u,d]) + bias[u]
//   A1 = log2e*mu*w, A2 = -0.5*log2e*w, w = 1/s^2
//   bias = log2e*(-0.5*sum mu^2 w - sum log s - D*0.5*log(2pi))
// out = exp2(acc). x_d is block-uniform -> s_load'ed; 2 VALU FMAs per (b,u,d).

#define TPB 256
#define DD 16
#define UPT 2      // u's per thread -> float2 loads/stores, 66 param VGPRs
#define BPB 32     // b rows per block

static constexpr float L2E   = 1.4426950408889634f;   // log2(e)
static constexpr float HL2PI = 0.91893853320467274f;  // 0.5*ln(2*pi)

// P layout: [2*D+1][U]. rows 0..15 = A1[d], 16..31 = A2[d], 32 = bias.
// One thread per (u,d); bias via 16-lane shfl reduction.
__global__ __launch_bounds__(TPB) void mva_precompute(
    const float* __restrict__ units, const float* __restrict__ attn,
    float* __restrict__ P, int U)
{
    int g = blockIdx.x * TPB + threadIdx.x;
    int u = g >> 4, d = g & 15;
    float s  = fmaxf(attn[(size_t)u * DD * DD + d * (DD + 1)], 1e-6f);
    float w  = 1.f / (s * s);
    float mu = units[g];  // units[u*DD + d] == units[g]
    P[(size_t)d * U + u]        = L2E * mu * w;
    P[(size_t)(DD + d) * U + u] = -0.5f * L2E * w;
    float bn = -0.5f * mu * mu * w - logf(s);
    bn += __shfl_xor(bn, 1, 16);
    bn += __shfl_xor(bn, 2, 16);
    bn += __shfl_xor(bn, 4, 16);
    bn += __shfl_xor(bn, 8, 16);
    if (d == 0) P[(size_t)(2 * DD) * U + u] = L2E * (bn - DD * HL2PI);
}

template <bool USE_WS>
__global__ __launch_bounds__(TPB) void mva_main(
    const float* __restrict__ x,      // [B,1,D]
    const float* __restrict__ P,      // [33][U] when USE_WS
    const float* __restrict__ units,  // raw params when !USE_WS
    const float* __restrict__ attn,
    float* __restrict__ out, int U)
{
    const int u0 = blockIdx.y * (TPB * UPT) + threadIdx.x * UPT;
    const int b0 = blockIdx.x * BPB;

    float a1[UPT][DD], a2[UPT][DD], bias[UPT];

    if (USE_WS) {
#pragma unroll
        for (int d = 0; d < DD; ++d) {
            float2 v = *reinterpret_cast<const float2*>(P + (size_t)d * U + u0);
            a1[0][d] = v.x; a1[1][d] = v.y;
            float2 w = *reinterpret_cast<const float2*>(P + (size_t)(DD + d) * U + u0);
            a2[0][d] = w.x; a2[1][d] = w.y;
        }
        float2 bv = *reinterpret_cast<const float2*>(P + (size_t)(2 * DD) * U + u0);
        bias[0] = bv.x; bias[1] = bv.y;
    } else {
#pragma unroll
        for (int i = 0; i < UPT; ++i) {
            int u = u0 + i;
            float bn = 0.f;
#pragma unroll
            for (int d = 0; d < DD; ++d) {
                float s  = fmaxf(attn[(size_t)u * DD * DD + d * (DD + 1)], 1e-6f);
                float w  = 1.f / (s * s);
                float mu = units[u * DD + d];
                a1[i][d] = L2E * mu * w;
                a2[i][d] = -0.5f * L2E * w;
                bn += -0.5f * mu * mu * w - logf(s);
            }
            bias[i] = L2E * (bn - DD * HL2PI);
        }
    }

    const float* xb = x + (size_t)b0 * DD;  // block-uniform base

#pragma unroll 4
    for (int b = 0; b < BPB; ++b) {
        // Block-uniform addresses -> scalar loads into SGPRs.
        float4 x0 = *reinterpret_cast<const float4*>(xb + b * DD + 0);
        float4 x1 = *reinterpret_cast<const float4*>(xb + b * DD + 4);
        float4 x2 = *reinterpret_cast<const float4*>(xb + b * DD + 8);
        float4 x3 = *reinterpret_cast<const float4*>(xb + b * DD + 12);
        float xr[DD] = {x0.x, x0.y, x0.z, x0.w, x1.x, x1.y, x1.z, x1.w,
                        x2.x, x2.y, x2.z, x2.w, x3.x, x3.y, x3.z, x3.w};
        float acc[UPT];
#pragma unroll
        for (int i = 0; i < UPT; ++i) acc[i] = bias[i];
#pragma unroll
        for (int d = 0; d < DD; ++d) {
#pragma unroll
            for (int i = 0; i < UPT; ++i) {
                // x*(a1 + x*a2): 2 FMAs, each with exactly 1 scalar operand
                float t = fmaf(xr[d], a2[i][d], a1[i][d]);
                acc[i]  = fmaf(xr[d], t, acc[i]);
            }
        }
        float2 o;
        o.x = __builtin_amdgcn_exp2f(acc[0]);
        o.y = __builtin_amdgcn_exp2f(acc[1]);
        *reinterpret_cast<float2*>(out + (size_t)(b0 + b) * U + u0) = o;
    }
}

extern "C" void kernel_launch(void* const* d_in, const int* in_sizes, int n_in,
                              void* d_out, int out_size, void* d_ws, size_t ws_size,
                              hipStream_t stream) {
    const float* x     = (const float*)d_in[0];  // [B,1,D]
    const float* units = (const float*)d_in[1];  // [U,D]
    const float* attn  = (const float*)d_in[2];  // [U,D,D]
    float* out = (float*)d_out;

    const int B = in_sizes[0] / DD;  // 4096
    const int U = in_sizes[1] / DD;  // 4096

    dim3 grid(B / BPB, U / (TPB * UPT));  // (128, 8) = 1024 blocks
    size_t pbytes = (size_t)(2 * DD + 1) * U * sizeof(float);

    if (ws_size >= pbytes) {
        float* P = (float*)d_ws;
        mva_precompute<<<(U * DD) / TPB, TPB, 0, stream>>>(units, attn, P, U);
        mva_main<true><<<grid, TPB, 0, stream>>>(x, P, units, attn, out, U);
    } else {
        mva_main<false><<<grid, TPB, 0, stream>>>(x, nullptr, units, attn, out, U);
    }
}

// Round 3
// 28.644 us; speedup vs baseline: 1.1102x; 1.1102x over previous
//
#include <hip/hip_runtime.h>
#include <hip/hip_bf16.h>
#include <math.h>

// MultiVariateAttention: out[b,u] = exp(mvn_logpdf(x[b]; mu[u], diag(s[u])))
// B = U = 4096, D = 16, fp32 in/out.
//
// log2(out[b,u]) = sum_d x_d*(A1[u,d] + x_d*A2[u,d]) + bias[u]
//   A1 = log2e*mu*w, A2 = -0.5*log2e*w, w = 1/s^2
//   bias = log2e*(-0.5*sum mu^2 w - sum log s - D*0.5*log(2pi))
// out = exp2(acc).
//
// Key structural rule: x comes from LDS (lgkmcnt) so the b-loop contains NO
// vmcnt waits — output stores (vmcnt, in-order counter) are never awaited
// inside the loop and stream continuously to HBM.

#define TPB 256
#define DD 16
#define UPT 2      // u's per thread: params = 66 VGPR, float2 stores
#define BPB 32     // b rows per block -> grid 1024 = 4 blocks/CU

static constexpr float L2E   = 1.4426950408889634f;   // log2(e)
static constexpr float HL2PI = 0.91893853320467274f;  // 0.5*ln(2*pi)

// P layout: [2*D+1][U]. rows 0..15 = A1[d], 16..31 = A2[d], 32 = bias.
__global__ __launch_bounds__(TPB) void mva_precompute(
    const float* __restrict__ units, const float* __restrict__ attn,
    float* __restrict__ P, int U)
{
    int g = blockIdx.x * TPB + threadIdx.x;
    int u = g >> 4, d = g & 15;
    float s  = fmaxf(attn[(size_t)u * DD * DD + d * (DD + 1)], 1e-6f);
    float w  = 1.f / (s * s);
    float mu = units[g];
    P[(size_t)d * U + u]        = L2E * mu * w;
    P[(size_t)(DD + d) * U + u] = -0.5f * L2E * w;
    float bn = -0.5f * mu * mu * w - logf(s);
    bn += __shfl_xor(bn, 1, 16);
    bn += __shfl_xor(bn, 2, 16);
    bn += __shfl_xor(bn, 4, 16);
    bn += __shfl_xor(bn, 8, 16);
    if (d == 0) P[(size_t)(2 * DD) * U + u] = L2E * (bn - DD * HL2PI);
}

template <bool USE_WS>
__global__ __launch_bounds__(TPB, 4) void mva_main(
    const float* __restrict__ x,      // [B,1,D]
    const float* __restrict__ P,      // [33][U] when USE_WS
    const float* __restrict__ units,  // raw params when !USE_WS
    const float* __restrict__ attn,
    float* __restrict__ out, int U)
{
    const int u0 = blockIdx.y * (TPB * UPT) + threadIdx.x * UPT;
    const int b0 = blockIdx.x * BPB;

    // Stage x tile in LDS FIRST (these vector loads + P loads overlap; the
    // single vmcnt/lgkm drain below is the only wait in the kernel).
    __shared__ float xs[BPB][DD];
    for (int idx = threadIdx.x; idx < BPB * DD; idx += TPB) {
        xs[idx >> 4][idx & 15] = x[(size_t)b0 * DD + idx];
    }

    float a1[UPT][DD], a2[UPT][DD], bias[UPT];
    if (USE_WS) {
#pragma unroll
        for (int d = 0; d < DD; ++d) {
            float2 v = *reinterpret_cast<const float2*>(P + (size_t)d * U + u0);
            a1[0][d] = v.x; a1[1][d] = v.y;
            float2 w = *reinterpret_cast<const float2*>(P + (size_t)(DD + d) * U + u0);
            a2[0][d] = w.x; a2[1][d] = w.y;
        }
        float2 bv = *reinterpret_cast<const float2*>(P + (size_t)(2 * DD) * U + u0);
        bias[0] = bv.x; bias[1] = bv.y;
    } else {
#pragma unroll
        for (int i = 0; i < UPT; ++i) {
            int u = u0 + i;
            float bn = 0.f;
#pragma unroll
            for (int d = 0; d < DD; ++d) {
                float s  = fmaxf(attn[(size_t)u * DD * DD + d * (DD + 1)], 1e-6f);
                float w  = 1.f / (s * s);
                float mu = units[u * DD + d];
                a1[i][d] = L2E * mu * w;
                a2[i][d] = -0.5f * L2E * w;
                bn += -0.5f * mu * mu * w - logf(s);
            }
            bias[i] = L2E * (bn - DD * HL2PI);
        }
    }
    __syncthreads();

#pragma unroll 2
    for (int b = 0; b < BPB; ++b) {
        float acc[UPT];
#pragma unroll
        for (int i = 0; i < UPT; ++i) acc[i] = bias[i];
#pragma unroll
        for (int j = 0; j < 4; ++j) {
            // All 64 lanes read the same LDS address -> broadcast, no conflict.
            float4 xv = *reinterpret_cast<const float4*>(&xs[b][4 * j]);
#pragma unroll
            for (int k = 0; k < 4; ++k) {
                float xd = (&xv.x)[k];
                int d = 4 * j + k;
#pragma unroll
                for (int i = 0; i < UPT; ++i) {
                    float t = fmaf(xd, a2[i][d], a1[i][d]);
                    acc[i]  = fmaf(xd, t, acc[i]);
                }
            }
        }
        float2 o;
        o.x = __builtin_amdgcn_exp2f(acc[0]);
        o.y = __builtin_amdgcn_exp2f(acc[1]);
        *reinterpret_cast<float2*>(out + (size_t)(b0 + b) * U + u0) = o;
    }
}

extern "C" void kernel_launch(void* const* d_in, const int* in_sizes, int n_in,
                              void* d_out, int out_size, void* d_ws, size_t ws_size,
                              hipStream_t stream) {
    const float* x     = (const float*)d_in[0];  // [B,1,D]
    const float* units = (const float*)d_in[1];  // [U,D]
    const float* attn  = (const float*)d_in[2];  // [U,D,D]
    float* out = (float*)d_out;

    const int B = in_sizes[0] / DD;  // 4096
    const int U = in_sizes[1] / DD;  // 4096

    dim3 grid(B / BPB, U / (TPB * UPT));  // (128, 8) = 1024 blocks = 4/CU
    size_t pbytes = (size_t)(2 * DD + 1) * U * sizeof(float);

    if (ws_size >= pbytes) {
        float* P = (float*)d_ws;
        mva_precompute<<<(U * DD) / TPB, TPB, 0, stream>>>(units, attn, P, U);
        mva_main<true><<<grid, TPB, 0, stream>>>(x, P, units, attn, out, U);
    } else {
        mva_main<false><<<grid, TPB, 0, stream>>>(x, nullptr, units, attn, out, U);
    }
}